// Round 1
// baseline (3497.548 us; speedup 1.0000x reference)
//
#include <hip/hip_runtime.h>

#define HW 256
#define BATCH 8
#define C 64
#define HO 244

// h1/h2 layout: [b][c][h][w], plane = 65536 floats

__global__ __launch_bounds__(256) void conv1_kernel(
    const float* __restrict__ x, const float* __restrict__ W1,
    const float* __restrict__ b1, float* __restrict__ h1)
{
    int idx = blockIdx.x * 256 + threadIdx.x;   // over B*H*W = 524288
    int b   = idx >> 16;
    int pos = idx & 0xFFFF;
    int h = pos >> 8;
    int w = pos & 0xFF;

    float v[9];
#pragma unroll
    for (int i = 0; i < 3; ++i)
#pragma unroll
        for (int j = 0; j < 3; ++j) {
            int hh = h + i - 1, ww = w + j - 1;
            bool ok = (hh >= 0) && (hh < HW) && (ww >= 0) && (ww < HW);
            v[i * 3 + j] = ok ? x[(b << 16) + hh * HW + ww] : 0.f;
        }

#pragma unroll 8
    for (int co = 0; co < C; ++co) {
        float a = b1[co];
#pragma unroll
        for (int t = 0; t < 9; ++t) a += v[t] * W1[co * 9 + t];
        h1[((b * C + co) << 16) + pos] = fmaxf(a, 0.f);
    }
}

__global__ __launch_bounds__(256) void conv2_kernel(
    const float* __restrict__ h1, const float* __restrict__ W2,
    const float* __restrict__ b2, float* __restrict__ h2)
{
    int b = blockIdx.z;
    int h = blockIdx.y * 16 + (threadIdx.x >> 4);
    int w = blockIdx.x * 16 + (threadIdx.x & 15);

    float acc[C];
#pragma unroll
    for (int co = 0; co < C; ++co) acc[co] = 0.f;

    for (int ci = 0; ci < C; ++ci) {
        const float* __restrict__ src = h1 + ((b * C + ci) << 16);
        float v[9];
#pragma unroll
        for (int i = 0; i < 3; ++i)
#pragma unroll
            for (int j = 0; j < 3; ++j) {
                int hh = h + i - 1, ww = w + j - 1;
                bool ok = (hh >= 0) && (hh < HW) && (ww >= 0) && (ww < HW);
                v[i * 3 + j] = ok ? src[hh * HW + ww] : 0.f;
            }
        // weights: block-uniform indices -> scalar loads
        const float* __restrict__ wp = W2 + ci * 9;
#pragma unroll
        for (int co = 0; co < C; ++co) {
            float a = acc[co];
#pragma unroll
            for (int t = 0; t < 9; ++t) a += v[t] * wp[co * 576 + t];
            acc[co] = a;
        }
    }

    int pos = h * HW + w;
#pragma unroll
    for (int co = 0; co < C; ++co)
        h2[((b * C + co) << 16) + pos] = fmaxf(acc[co] + b2[co], 0.f);
}

// Fused conv3 (evaluated only at cropped positions h=ho+6) + patch contraction.
// y[b,ho,wo] = sum_{u,v} x[b,ho+u,wo+v] * (b3[uv] + conv3(h2)[b,uv,ho+6,wo+6])
__global__ __launch_bounds__(256) void conv3_nlm_kernel(
    const float* __restrict__ x, const float* __restrict__ h2,
    const float* __restrict__ W3, const float* __restrict__ b3,
    float* __restrict__ y)
{
    int b  = blockIdx.z;
    int ho = blockIdx.y * 16 + (threadIdx.x >> 4);
    int wo = blockIdx.x * 16 + (threadIdx.x & 15);
    if (ho >= HO || wo >= HO) return;

    float acc = 0.f;
    for (int u = 0; u < 13; ++u) {          // uv = u*13 + q, chunk over u
        float s[13];
#pragma unroll
        for (int q = 0; q < 13; ++q) s[q] = b3[u * 13 + q];

        for (int ci = 0; ci < C; ++ci) {
            // conv3 3x3 window at (ho+6, wo+6): rows ho+5..ho+7, always in-bounds
            const float* __restrict__ src =
                h2 + ((b * C + ci) << 16) + (ho + 5) * HW + (wo + 5);
            float hv[9];
#pragma unroll
            for (int i = 0; i < 3; ++i)
#pragma unroll
                for (int j = 0; j < 3; ++j)
                    hv[i * 3 + j] = src[i * HW + j];

            const float* __restrict__ wp = W3 + (u * 13) * 576 + ci * 9;
#pragma unroll
            for (int q = 0; q < 13; ++q) {
                float a = s[q];
#pragma unroll
                for (int t = 0; t < 9; ++t) a += hv[t] * wp[q * 576 + t];
                s[q] = a;
            }
        }

        const float* __restrict__ xr = x + (b << 16) + (ho + u) * HW + wo;
#pragma unroll
        for (int q = 0; q < 13; ++q) acc += s[q] * xr[q];
    }
    y[(b * HO + ho) * HO + wo] = acc;
}

extern "C" void kernel_launch(void* const* d_in, const int* in_sizes, int n_in,
                              void* d_out, int out_size, void* d_ws, size_t ws_size,
                              hipStream_t stream) {
    const float* x  = (const float*)d_in[0];
    const float* W1 = (const float*)d_in[1];
    const float* b1 = (const float*)d_in[2];
    const float* W2 = (const float*)d_in[3];
    const float* b2 = (const float*)d_in[4];
    const float* W3 = (const float*)d_in[5];
    const float* b3 = (const float*)d_in[6];
    float* out = (float*)d_out;

    float* h1 = (float*)d_ws;                              // 134217728 B
    float* h2 = h1 + (size_t)BATCH * C * HW * HW;          // 134217728 B

    conv1_kernel<<<2048, 256, 0, stream>>>(x, W1, b1, h1);
    conv2_kernel<<<dim3(16, 16, 8), 256, 0, stream>>>(h1, W2, b2, h2);
    conv3_nlm_kernel<<<dim3(16, 16, 8), 256, 0, stream>>>(x, h2, W3, b3, out);
}

// Round 2
// 1007.592 us; speedup vs baseline: 3.4712x; 3.4712x over previous
//
#include <hip/hip_runtime.h>

#define HW 256
#define BATCH 8
#define C 64
#define HO 244
#define NPAD 192
#define KTOT 576

typedef __bf16 bf16x8 __attribute__((ext_vector_type(8)));
typedef float f32x16 __attribute__((ext_vector_type(16)));
typedef unsigned short us8 __attribute__((ext_vector_type(8)));

__device__ inline unsigned short f2bf(float f) {
    union { float f; unsigned int u; } c; c.f = f;
    unsigned int lsb = (c.u >> 16) & 1;
    c.u += 0x7fffu + lsb;
    return (unsigned short)(c.u >> 16);
}

// ---------------- conv1: 1->64, fp32, h1 NCHW ----------------
__global__ __launch_bounds__(256) void conv1_kernel(
    const float* __restrict__ x, const float* __restrict__ W1,
    const float* __restrict__ b1, float* __restrict__ h1)
{
    int idx = blockIdx.x * 256 + threadIdx.x;
    int b   = idx >> 16;
    int pos = idx & 0xFFFF;
    int h = pos >> 8;
    int w = pos & 0xFF;

    float v[9];
#pragma unroll
    for (int i = 0; i < 3; ++i)
#pragma unroll
        for (int j = 0; j < 3; ++j) {
            int hh = h + i - 1, ww = w + j - 1;
            bool ok = (hh >= 0) && (hh < HW) && (ww >= 0) && (ww < HW);
            v[i * 3 + j] = ok ? x[(b << 16) + hh * HW + ww] : 0.f;
        }

#pragma unroll 8
    for (int co = 0; co < C; ++co) {
        float a = b1[co];
#pragma unroll
        for (int t = 0; t < 9; ++t) a += v[t] * W1[co * 9 + t];
        h1[(((size_t)b * C + co) << 16) + pos] = fmaxf(a, 0.f);
    }
}

// ---------------- conv2: 64->64, fp32 math, writes h2 bf16 NHWC ----------------
__global__ __launch_bounds__(256) void conv2_kernel(
    const float* __restrict__ h1, const float* __restrict__ W2,
    const float* __restrict__ b2, unsigned short* __restrict__ h2)
{
    int b = blockIdx.z;
    int h = blockIdx.y * 16 + (threadIdx.x >> 4);
    int w = blockIdx.x * 16 + (threadIdx.x & 15);

    float acc[C];
#pragma unroll
    for (int co = 0; co < C; ++co) acc[co] = 0.f;

    for (int ci = 0; ci < C; ++ci) {
        const float* __restrict__ src = h1 + (((size_t)b * C + ci) << 16);
        float v[9];
#pragma unroll
        for (int i = 0; i < 3; ++i)
#pragma unroll
            for (int j = 0; j < 3; ++j) {
                int hh = h + i - 1, ww = w + j - 1;
                bool ok = (hh >= 0) && (hh < HW) && (ww >= 0) && (ww < HW);
                v[i * 3 + j] = ok ? src[hh * HW + ww] : 0.f;
            }
        const float* __restrict__ wp = W2 + ci * 9;
#pragma unroll
        for (int co = 0; co < C; ++co) {
            float a = acc[co];
#pragma unroll
            for (int t = 0; t < 9; ++t) a += v[t] * wp[co * 576 + t];
            acc[co] = a;
        }
    }

    size_t base = (((size_t)b * HW + h) * HW + w) * C;
#pragma unroll
    for (int co = 0; co < C; ++co)
        h2[base + co] = f2bf(fmaxf(acc[co] + b2[co], 0.f));
}

// ---------------- W3 repack: Bg[n][k] bf16, k = (i*3+j)*64 + ci ----------------
__global__ __launch_bounds__(256) void repack_w3_kernel(
    const float* __restrict__ W3, unsigned short* __restrict__ Bg)
{
    int idx = blockIdx.x * 256 + threadIdx.x;   // over NPAD*KTOT = 110592
    if (idx >= NPAD * KTOT) return;
    int n = idx / KTOT;
    int k = idx - n * KTOT;
    int ij = k >> 6;
    int ci = k & 63;
    float v = (n < 169) ? W3[((size_t)n * C + ci) * 9 + ij] : 0.f;
    Bg[(size_t)n * KTOT + k] = f2bf(v);
}

// ---------------- fused conv3 + NLM contraction, bf16 MFMA implicit GEMM ----
// Workgroup: M=128 (2 output rows x 64 wo), N=192 (169 padded), K=576.
// wave (w>>1) -> output row half, (w&1) -> N-half (96).
__global__ __launch_bounds__(256, 3) void conv3_mfma_kernel(
    const float* __restrict__ x, const unsigned short* __restrict__ h2,
    const unsigned short* __restrict__ Bg, const float* __restrict__ b3,
    float* __restrict__ y)
{
    __shared__ unsigned short Ash[128 * 72];   // stride 72 elems (144 B)
    __shared__ unsigned short Bsh[NPAD * 72];
    __shared__ float red[4][64];

    const int t = threadIdx.x;
    const int lane = t & 63;
    const int wave = t >> 6;
    const int b   = blockIdx.z;
    const int ho0 = blockIdx.y * 2;
    const int wo0 = blockIdx.x * 64;

    const int col   = lane & 31;
    const int khalf = lane >> 5;

    const int mrow_base = (wave >> 1) * 64;
    const int nbase     = (wave & 1) * 96;

    f32x16 acc[2][3];
#pragma unroll
    for (int mi = 0; mi < 2; ++mi)
#pragma unroll
        for (int ni = 0; ni < 3; ++ni)
#pragma unroll
            for (int r = 0; r < 16; ++r) acc[mi][ni][r] = 0.f;

    for (int chunk = 0; chunk < 9; ++chunk) {
        const int ii = chunk / 3, jj = chunk - ii * 3;
        __syncthreads();
        // stage A: 128 rows x 64 bf16 (8 KB x2), contiguous per output row
#pragma unroll
        for (int it = 0; it < 4; ++it) {
            int li = it * 256 + t;
            int m = li >> 3, g = li & 7;
            int row_sel = m >> 6, wo_t = m & 63;
            size_t src = (((size_t)b * HW + (ho0 + row_sel + 5 + ii)) * HW
                          + (wo0 + 5 + jj + wo_t)) * C + g * 8;
            uint4 v = *(const uint4*)(h2 + src);
            *(uint4*)(Ash + m * 72 + g * 8) = v;
        }
        // stage B: 192 rows x 64 bf16
#pragma unroll
        for (int it = 0; it < 6; ++it) {
            int li = it * 256 + t;
            int n = li >> 3, g = li & 7;
            uint4 v = *(const uint4*)(Bg + (size_t)n * KTOT + chunk * 64 + g * 8);
            *(uint4*)(Bsh + n * 72 + g * 8) = v;
        }
        __syncthreads();
#pragma unroll
        for (int ks = 0; ks < 4; ++ks) {
            const int koff = ks * 16 + khalf * 8;
            bf16x8 a0 = __builtin_bit_cast(bf16x8, *(const us8*)(Ash + (mrow_base + col) * 72 + koff));
            bf16x8 a1 = __builtin_bit_cast(bf16x8, *(const us8*)(Ash + (mrow_base + 32 + col) * 72 + koff));
            bf16x8 b0 = __builtin_bit_cast(bf16x8, *(const us8*)(Bsh + (nbase + col) * 72 + koff));
            bf16x8 b1 = __builtin_bit_cast(bf16x8, *(const us8*)(Bsh + (nbase + 32 + col) * 72 + koff));
            bf16x8 b2v = __builtin_bit_cast(bf16x8, *(const us8*)(Bsh + (nbase + 64 + col) * 72 + koff));
            acc[0][0] = __builtin_amdgcn_mfma_f32_32x32x16_bf16(a0, b0, acc[0][0], 0, 0, 0);
            acc[0][1] = __builtin_amdgcn_mfma_f32_32x32x16_bf16(a0, b1, acc[0][1], 0, 0, 0);
            acc[0][2] = __builtin_amdgcn_mfma_f32_32x32x16_bf16(a0, b2v, acc[0][2], 0, 0, 0);
            acc[1][0] = __builtin_amdgcn_mfma_f32_32x32x16_bf16(a1, b0, acc[1][0], 0, 0, 0);
            acc[1][1] = __builtin_amdgcn_mfma_f32_32x32x16_bf16(a1, b1, acc[1][1], 0, 0, 0);
            acc[1][2] = __builtin_amdgcn_mfma_f32_32x32x16_bf16(a1, b2v, acc[1][2], 0, 0, 0);
        }
    }

    // ---- epilogue: y[m] = sum_{q<169} (acc[m][q] + b3[q]) * x[b, ho+u, wo+v]
    const int ho_pix = ho0 + (wave >> 1);
    const float* __restrict__ xplane = x + ((size_t)b << 16);

    int   qv[3], uo[3], vo[3];
    float b3v[3];
#pragma unroll
    for (int ni = 0; ni < 3; ++ni) {
        int q = nbase + ni * 32 + col;
        qv[ni] = q;
        int u = q / 13;
        uo[ni] = u;
        vo[ni] = q - u * 13;
        b3v[ni] = (q < 169) ? b3[q] : 0.f;
    }

    float partial[2][16];
#pragma unroll
    for (int mi = 0; mi < 2; ++mi)
#pragma unroll
        for (int r = 0; r < 16; ++r) {
            int mrow = mi * 32 + (r & 3) + ((r >> 2) << 3) + (khalf << 2);
            int wo_pix = wo0 + mrow;
            bool wok = wo_pix < HO;
            float p = 0.f;
#pragma unroll
            for (int ni = 0; ni < 3; ++ni) {
                if (qv[ni] < 169 && wok) {
                    float s = acc[mi][ni][r] + b3v[ni];
                    p += s * xplane[(ho_pix + uo[ni]) * HW + wo_pix + vo[ni]];
                }
            }
            partial[mi][r] = p;
        }

#pragma unroll
    for (int mi = 0; mi < 2; ++mi)
#pragma unroll
        for (int r = 0; r < 16; ++r) {
            float p = partial[mi][r];
#pragma unroll
            for (int d = 1; d < 32; d <<= 1) p += __shfl_xor(p, d, 64);
            partial[mi][r] = p;
        }

    if (col == 0) {
#pragma unroll
        for (int mi = 0; mi < 2; ++mi)
#pragma unroll
            for (int r = 0; r < 16; ++r) {
                int mrow = mi * 32 + (r & 3) + ((r >> 2) << 3) + (khalf << 2);
                red[wave][mrow] = partial[mi][r];
            }
    }
    __syncthreads();

    if (t < 128) {
        int row_sel = t >> 6, m = t & 63;
        float val = red[row_sel * 2][m] + red[row_sel * 2 + 1][m];
        int wo = wo0 + m, ho = ho0 + row_sel;
        if (wo < HO)
            y[((size_t)b * HO + ho) * HO + wo] = val;
    }
}

extern "C" void kernel_launch(void* const* d_in, const int* in_sizes, int n_in,
                              void* d_out, int out_size, void* d_ws, size_t ws_size,
                              hipStream_t stream) {
    const float* x  = (const float*)d_in[0];
    const float* W1 = (const float*)d_in[1];
    const float* b1 = (const float*)d_in[2];
    const float* W2 = (const float*)d_in[3];
    const float* b2 = (const float*)d_in[4];
    const float* W3 = (const float*)d_in[5];
    const float* b3 = (const float*)d_in[6];
    float* out = (float*)d_out;

    float* h1 = (float*)d_ws;                                   // 134 MB fp32 NCHW
    unsigned short* h2  = (unsigned short*)(h1 + (size_t)BATCH * C * HW * HW);  // 67 MB bf16 NHWC
    unsigned short* W3r = h2 + (size_t)BATCH * HW * HW * C;     // 216 KB

    repack_w3_kernel<<<(NPAD * KTOT + 255) / 256, 256, 0, stream>>>(W3, W3r);
    conv1_kernel<<<2048, 256, 0, stream>>>(x, W1, b1, h1);
    conv2_kernel<<<dim3(16, 16, 8), 256, 0, stream>>>(h1, W2, b2, h2);
    conv3_mfma_kernel<<<dim3(4, 122, 8), 256, 0, stream>>>(x, h2, W3r, b3, out);
}

// Round 3
// 406.657 us; speedup vs baseline: 8.6007x; 2.4777x over previous
//
#include <hip/hip_runtime.h>

#define HW 256
#define HP 258
#define BATCH 8
#define C 64
#define HO 244
#define NPAD 192
#define KTOT 576

typedef __bf16 bf16x8 __attribute__((ext_vector_type(8)));
typedef float f32x16 __attribute__((ext_vector_type(16)));
typedef unsigned short us8 __attribute__((ext_vector_type(8)));

__device__ inline unsigned short f2bf(float f) {
    union { float f; unsigned int u; } c; c.f = f;
    unsigned int lsb = (c.u >> 16) & 1;
    c.u += 0x7fffu + lsb;
    return (unsigned short)(c.u >> 16);
}

// ---------------- conv1: 1->64, fp32 math, writes bf16 NHWC into padded 258x258 ----
// thread = (pixel, 8-channel group); border pixels write zeros.
__global__ __launch_bounds__(256) void conv1_kernel(
    const float* __restrict__ x, const float* __restrict__ W1,
    const float* __restrict__ b1, unsigned short* __restrict__ h1p)
{
    int t = threadIdx.x;
    int p = blockIdx.x * 32 + (t >> 3);
    if (p >= BATCH * HP * HP) return;
    int b   = p / (HP * HP);
    int rem = p - b * HP * HP;
    int hp  = rem / HP;
    int wp  = rem - hp * HP;
    int cg  = (t & 7) * 8;
    size_t dst = (size_t)p * C + cg;

    if (hp == 0 || hp == HP - 1 || wp == 0 || wp == HP - 1) {
        *(uint4*)(h1p + dst) = make_uint4(0, 0, 0, 0);
        return;
    }
    int h = hp - 1, w = wp - 1;

    float v[9];
#pragma unroll
    for (int i = 0; i < 3; ++i)
#pragma unroll
        for (int j = 0; j < 3; ++j) {
            int hh = h + i - 1, ww = w + j - 1;
            bool ok = (hh >= 0) && (hh < HW) && (ww >= 0) && (ww < HW);
            v[i * 3 + j] = ok ? x[((size_t)b << 16) + hh * HW + ww] : 0.f;
        }

    unsigned short outv[8];
#pragma unroll
    for (int u = 0; u < 8; ++u) {
        int co = cg + u;
        float a = b1[co];
#pragma unroll
        for (int q = 0; q < 9; ++q) a += v[q] * W1[co * 9 + q];
        outv[u] = f2bf(fmaxf(a, 0.f));
    }
    *(uint4*)(h1p + dst) = *(uint4*)outv;
}

// ---------------- W2 repack: [n=64][k=576] bf16, k = ij*64 + ci ----------------
__global__ __launch_bounds__(256) void repack_w2_kernel(
    const float* __restrict__ W2, unsigned short* __restrict__ Bg)
{
    int idx = blockIdx.x * 256 + threadIdx.x;   // over 64*576 = 36864
    if (idx >= C * KTOT) return;
    int n = idx / KTOT;
    int k = idx - n * KTOT;
    int ij = k >> 6;
    int ci = k & 63;
    Bg[idx] = f2bf(W2[((size_t)n * C + ci) * 9 + ij]);
}

// ---------------- W3 repack: [n=192][k=576] bf16 ----------------
__global__ __launch_bounds__(256) void repack_w3_kernel(
    const float* __restrict__ W3, unsigned short* __restrict__ Bg)
{
    int idx = blockIdx.x * 256 + threadIdx.x;   // over NPAD*KTOT
    if (idx >= NPAD * KTOT) return;
    int n = idx / KTOT;
    int k = idx - n * KTOT;
    int ij = k >> 6;
    int ci = k & 63;
    float v = (n < 169) ? W3[((size_t)n * C + ci) * 9 + ij] : 0.f;
    Bg[idx] = f2bf(v);
}

// ---------------- conv2: bf16 MFMA implicit GEMM, M=128 N=64 K=576 ----------------
__global__ __launch_bounds__(256, 3) void conv2_mfma_kernel(
    const unsigned short* __restrict__ h1p, const unsigned short* __restrict__ W2r,
    const float* __restrict__ b2, unsigned short* __restrict__ h2)
{
    __shared__ unsigned short Ash[128 * 72];
    __shared__ unsigned short Bsh[64 * 72];

    const int t = threadIdx.x;
    const int lane = t & 63;
    const int wave = t >> 6;
    const int b  = blockIdx.z;
    const int h0 = blockIdx.y * 2;
    const int w0 = blockIdx.x * 64;

    const int col   = lane & 31;
    const int khalf = lane >> 5;
    const int mbase = wave * 32;

    f32x16 acc[2];
#pragma unroll
    for (int ni = 0; ni < 2; ++ni)
#pragma unroll
        for (int r = 0; r < 16; ++r) acc[ni][r] = 0.f;

    for (int chunk = 0; chunk < 9; ++chunk) {
        const int ii = chunk / 3, jj = chunk - ii * 3;
        __syncthreads();
#pragma unroll
        for (int it = 0; it < 4; ++it) {
            int li = it * 256 + t;
            int m = li >> 3, g = li & 7;
            int hh = h0 + (m >> 6) + ii;          // padded coords
            int ww = w0 + (m & 63) + jj;
            size_t src = (((size_t)b * HP + hh) * HP + ww) * C + g * 8;
            *(uint4*)(Ash + m * 72 + g * 8) = *(const uint4*)(h1p + src);
        }
#pragma unroll
        for (int it = 0; it < 2; ++it) {
            int li = it * 256 + t;
            int n = li >> 3, g = li & 7;
            *(uint4*)(Bsh + n * 72 + g * 8) =
                *(const uint4*)(W2r + (size_t)n * KTOT + chunk * 64 + g * 8);
        }
        __syncthreads();
#pragma unroll
        for (int ks = 0; ks < 4; ++ks) {
            const int koff = ks * 16 + khalf * 8;
            bf16x8 a  = __builtin_bit_cast(bf16x8, *(const us8*)(Ash + (mbase + col) * 72 + koff));
            bf16x8 b0 = __builtin_bit_cast(bf16x8, *(const us8*)(Bsh + col * 72 + koff));
            bf16x8 b1 = __builtin_bit_cast(bf16x8, *(const us8*)(Bsh + (32 + col) * 72 + koff));
            acc[0] = __builtin_amdgcn_mfma_f32_32x32x16_bf16(a, b0, acc[0], 0, 0, 0);
            acc[1] = __builtin_amdgcn_mfma_f32_32x32x16_bf16(a, b1, acc[1], 0, 0, 0);
        }
    }

#pragma unroll
    for (int nb = 0; nb < 2; ++nb) {
        int n = nb * 32 + col;
        float bias = b2[n];
#pragma unroll
        for (int r = 0; r < 16; ++r) {
            int m = mbase + (r & 3) + ((r >> 2) << 3) + (khalf << 2);
            int h = h0 + (m >> 6), w = w0 + (m & 63);
            float val = fmaxf(acc[nb][r] + bias, 0.f);
            h2[(((size_t)b * HW + h) * HW + w) * C + n] = f2bf(val);
        }
    }
}

// ---------------- fused conv3 + NLM contraction (unchanged from round 2) ----------
__global__ __launch_bounds__(256, 3) void conv3_mfma_kernel(
    const float* __restrict__ x, const unsigned short* __restrict__ h2,
    const unsigned short* __restrict__ Bg, const float* __restrict__ b3,
    float* __restrict__ y)
{
    __shared__ unsigned short Ash[128 * 72];
    __shared__ unsigned short Bsh[NPAD * 72];
    __shared__ float red[4][64];

    const int t = threadIdx.x;
    const int lane = t & 63;
    const int wave = t >> 6;
    const int b   = blockIdx.z;
    const int ho0 = blockIdx.y * 2;
    const int wo0 = blockIdx.x * 64;

    const int col   = lane & 31;
    const int khalf = lane >> 5;

    const int mrow_base = (wave >> 1) * 64;
    const int nbase     = (wave & 1) * 96;

    f32x16 acc[2][3];
#pragma unroll
    for (int mi = 0; mi < 2; ++mi)
#pragma unroll
        for (int ni = 0; ni < 3; ++ni)
#pragma unroll
            for (int r = 0; r < 16; ++r) acc[mi][ni][r] = 0.f;

    for (int chunk = 0; chunk < 9; ++chunk) {
        const int ii = chunk / 3, jj = chunk - ii * 3;
        __syncthreads();
#pragma unroll
        for (int it = 0; it < 4; ++it) {
            int li = it * 256 + t;
            int m = li >> 3, g = li & 7;
            int row_sel = m >> 6, wo_t = m & 63;
            size_t src = (((size_t)b * HW + (ho0 + row_sel + 5 + ii)) * HW
                          + (wo0 + 5 + jj + wo_t)) * C + g * 8;
            uint4 v = *(const uint4*)(h2 + src);
            *(uint4*)(Ash + m * 72 + g * 8) = v;
        }
#pragma unroll
        for (int it = 0; it < 6; ++it) {
            int li = it * 256 + t;
            int n = li >> 3, g = li & 7;
            uint4 v = *(const uint4*)(Bg + (size_t)n * KTOT + chunk * 64 + g * 8);
            *(uint4*)(Bsh + n * 72 + g * 8) = v;
        }
        __syncthreads();
#pragma unroll
        for (int ks = 0; ks < 4; ++ks) {
            const int koff = ks * 16 + khalf * 8;
            bf16x8 a0 = __builtin_bit_cast(bf16x8, *(const us8*)(Ash + (mrow_base + col) * 72 + koff));
            bf16x8 a1 = __builtin_bit_cast(bf16x8, *(const us8*)(Ash + (mrow_base + 32 + col) * 72 + koff));
            bf16x8 b0 = __builtin_bit_cast(bf16x8, *(const us8*)(Bsh + (nbase + col) * 72 + koff));
            bf16x8 b1 = __builtin_bit_cast(bf16x8, *(const us8*)(Bsh + (nbase + 32 + col) * 72 + koff));
            bf16x8 b2v = __builtin_bit_cast(bf16x8, *(const us8*)(Bsh + (nbase + 64 + col) * 72 + koff));
            acc[0][0] = __builtin_amdgcn_mfma_f32_32x32x16_bf16(a0, b0, acc[0][0], 0, 0, 0);
            acc[0][1] = __builtin_amdgcn_mfma_f32_32x32x16_bf16(a0, b1, acc[0][1], 0, 0, 0);
            acc[0][2] = __builtin_amdgcn_mfma_f32_32x32x16_bf16(a0, b2v, acc[0][2], 0, 0, 0);
            acc[1][0] = __builtin_amdgcn_mfma_f32_32x32x16_bf16(a1, b0, acc[1][0], 0, 0, 0);
            acc[1][1] = __builtin_amdgcn_mfma_f32_32x32x16_bf16(a1, b1, acc[1][1], 0, 0, 0);
            acc[1][2] = __builtin_amdgcn_mfma_f32_32x32x16_bf16(a1, b2v, acc[1][2], 0, 0, 0);
        }
    }

    const int ho_pix = ho0 + (wave >> 1);
    const float* __restrict__ xplane = x + ((size_t)b << 16);

    int   qv[3], uo[3], vo[3];
    float b3v[3];
#pragma unroll
    for (int ni = 0; ni < 3; ++ni) {
        int q = nbase + ni * 32 + col;
        qv[ni] = q;
        int u = q / 13;
        uo[ni] = u;
        vo[ni] = q - u * 13;
        b3v[ni] = (q < 169) ? b3[q] : 0.f;
    }

    float partial[2][16];
#pragma unroll
    for (int mi = 0; mi < 2; ++mi)
#pragma unroll
        for (int r = 0; r < 16; ++r) {
            int mrow = mi * 32 + (r & 3) + ((r >> 2) << 3) + (khalf << 2);
            int wo_pix = wo0 + mrow;
            bool wok = wo_pix < HO;
            float p = 0.f;
#pragma unroll
            for (int ni = 0; ni < 3; ++ni) {
                if (qv[ni] < 169 && wok) {
                    float s = acc[mi][ni][r] + b3v[ni];
                    p += s * xplane[(ho_pix + uo[ni]) * HW + wo_pix + vo[ni]];
                }
            }
            partial[mi][r] = p;
        }

#pragma unroll
    for (int mi = 0; mi < 2; ++mi)
#pragma unroll
        for (int r = 0; r < 16; ++r) {
            float p = partial[mi][r];
#pragma unroll
            for (int d = 1; d < 32; d <<= 1) p += __shfl_xor(p, d, 64);
            partial[mi][r] = p;
        }

    if (col == 0) {
#pragma unroll
        for (int mi = 0; mi < 2; ++mi)
#pragma unroll
            for (int r = 0; r < 16; ++r) {
                int mrow = mi * 32 + (r & 3) + ((r >> 2) << 3) + (khalf << 2);
                red[wave][mrow] = partial[mi][r];
            }
    }
    __syncthreads();

    if (t < 128) {
        int row_sel = t >> 6, m = t & 63;
        float val = red[row_sel * 2][m] + red[row_sel * 2 + 1][m];
        int wo = wo0 + m, ho = ho0 + row_sel;
        if (wo < HO)
            y[((size_t)b * HO + ho) * HO + wo] = val;
    }
}

extern "C" void kernel_launch(void* const* d_in, const int* in_sizes, int n_in,
                              void* d_out, int out_size, void* d_ws, size_t ws_size,
                              hipStream_t stream) {
    const float* x  = (const float*)d_in[0];
    const float* W1 = (const float*)d_in[1];
    const float* b1 = (const float*)d_in[2];
    const float* W2 = (const float*)d_in[3];
    const float* b2 = (const float*)d_in[4];
    const float* W3 = (const float*)d_in[5];
    const float* b3 = (const float*)d_in[6];
    float* out = (float*)d_out;

    unsigned short* h1p = (unsigned short*)d_ws;                 // 8*258*258*64 bf16 = 68.2 MB
    unsigned short* h2  = h1p + (size_t)BATCH * HP * HP * C;     // 8*256*256*64 bf16 = 67.1 MB
    unsigned short* W2r = h2 + (size_t)BATCH * HW * HW * C;      // 73.7 KB
    unsigned short* W3r = W2r + (size_t)C * KTOT;                // 221 KB

    repack_w2_kernel<<<(C * KTOT + 255) / 256, 256, 0, stream>>>(W2, W2r);
    repack_w3_kernel<<<(NPAD * KTOT + 255) / 256, 256, 0, stream>>>(W3, W3r);
    conv1_kernel<<<(BATCH * HP * HP + 31) / 32, 256, 0, stream>>>(x, W1, b1, h1p);
    conv2_mfma_kernel<<<dim3(4, 128, 8), 256, 0, stream>>>(h1p, W2r, b2, h2);
    conv3_mfma_kernel<<<dim3(4, 122, 8), 256, 0, stream>>>(x, h2, W3r, b3, out);
}

// Round 4
// 358.736 us; speedup vs baseline: 9.7496x; 1.1336x over previous
//
#include <hip/hip_runtime.h>

#define HW 256
#define HP 258
#define BATCH 8
#define C 64
#define HO 244
#define NPAD 192
#define KTOT 576

typedef __bf16 bf16x8 __attribute__((ext_vector_type(8)));
typedef float f32x16 __attribute__((ext_vector_type(16)));
typedef unsigned short us8 __attribute__((ext_vector_type(8)));

__device__ inline unsigned short f2bf(float f) {
    union { float f; unsigned int u; } c; c.f = f;
    unsigned int lsb = (c.u >> 16) & 1;
    c.u += 0x7fffu + lsb;
    return (unsigned short)(c.u >> 16);
}

// ---------------- conv1: 1->64, fp32 math, writes bf16 NHWC into padded 258x258 ----
__global__ __launch_bounds__(256) void conv1_kernel(
    const float* __restrict__ x, const float* __restrict__ W1,
    const float* __restrict__ b1, unsigned short* __restrict__ h1p)
{
    int t = threadIdx.x;
    int p = blockIdx.x * 32 + (t >> 3);
    if (p >= BATCH * HP * HP) return;
    int b   = p / (HP * HP);
    int rem = p - b * HP * HP;
    int hp  = rem / HP;
    int wp  = rem - hp * HP;
    int cg  = (t & 7) * 8;
    size_t dst = (size_t)p * C + cg;

    if (hp == 0 || hp == HP - 1 || wp == 0 || wp == HP - 1) {
        *(uint4*)(h1p + dst) = make_uint4(0, 0, 0, 0);
        return;
    }
    int h = hp - 1, w = wp - 1;

    float v[9];
#pragma unroll
    for (int i = 0; i < 3; ++i)
#pragma unroll
        for (int j = 0; j < 3; ++j) {
            int hh = h + i - 1, ww = w + j - 1;
            bool ok = (hh >= 0) && (hh < HW) && (ww >= 0) && (ww < HW);
            v[i * 3 + j] = ok ? x[((size_t)b << 16) + hh * HW + ww] : 0.f;
        }

    unsigned short outv[8];
#pragma unroll
    for (int u = 0; u < 8; ++u) {
        int co = cg + u;
        float a = b1[co];
#pragma unroll
        for (int q = 0; q < 9; ++q) a += v[q] * W1[co * 9 + q];
        outv[u] = f2bf(fmaxf(a, 0.f));
    }
    *(uint4*)(h1p + dst) = *(uint4*)outv;
}

// ---- W2 repack, fragment-coalesced: B2r[((kstep*2+khalf)*64 + n)*8 + e] ----
__global__ __launch_bounds__(256) void repack_w2_kernel(
    const float* __restrict__ W2, unsigned short* __restrict__ Bg)
{
    int idx = blockIdx.x * 256 + threadIdx.x;   // over 36*2*64*8 = 36864
    if (idx >= 36 * 2 * C * 8) return;
    int e = idx & 7;
    int r = idx >> 3;
    int n = r & 63;
    int s = r >> 6;
    int khalf = s & 1;
    int kstep = s >> 1;
    int chunk = kstep >> 2, ks = kstep & 3;
    int ci = ks * 16 + khalf * 8 + e;
    Bg[idx] = f2bf(W2[((size_t)n * C + ci) * 9 + chunk]);
}

// ---- W3 repack, fragment-coalesced: B3r[((kstep*2+khalf)*192 + n)*8 + e] ----
__global__ __launch_bounds__(256) void repack_w3_kernel(
    const float* __restrict__ W3, unsigned short* __restrict__ Bg)
{
    int idx = blockIdx.x * 256 + threadIdx.x;   // over 36*2*192*8 = 110592
    if (idx >= 36 * 2 * NPAD * 8) return;
    int e = idx & 7;
    int r = idx >> 3;
    int n = r % NPAD;
    int s = r / NPAD;
    int khalf = s & 1;
    int kstep = s >> 1;
    int chunk = kstep >> 2, ks = kstep & 3;
    int ci = ks * 16 + khalf * 8 + e;
    float v = (n < 169) ? W3[((size_t)n * C + ci) * 9 + chunk] : 0.f;
    Bg[idx] = f2bf(v);
}

// ---------------- conv2: A-tile-once MFMA implicit GEMM, M=128 N=64 K=576 ------
// Wave tile 64x32: mrow_base=(wave>>1)*64, nbase=(wave&1)*32.
__global__ __launch_bounds__(256, 4) void conv2_mfma_kernel(
    const unsigned short* __restrict__ h1p, const unsigned short* __restrict__ W2r,
    const float* __restrict__ b2, unsigned short* __restrict__ h2)
{
    __shared__ unsigned short Ash[264 * 72];   // 4 rows x 66 cols, ch-stride 72

    const int t = threadIdx.x;
    const int lane = t & 63;
    const int wave = t >> 6;
    const int b  = blockIdx.z;
    const int h0 = blockIdx.y * 2;
    const int w0 = blockIdx.x * 64;

    const int col   = lane & 31;
    const int khalf = lane >> 5;
    const int mrow_base = (wave >> 1) * 64;
    const int nbase     = (wave & 1) * 32;
    const int rsel      = mrow_base >> 6;

    f32x16 acc[2];
#pragma unroll
    for (int ai = 0; ai < 2; ++ai)
#pragma unroll
        for (int r = 0; r < 16; ++r) acc[ai][r] = 0.f;

    // stage full A-tile once: rows h0..h0+3 of padded plane, cols w0..w0+65
#pragma unroll
    for (int it = 0; it < 9; ++it) {
        int li = it * 256 + t;
        if (li < 264 * 8) {
            int p = li >> 3, g = li & 7;
            int row = p / 66, cl = p - row * 66;
            size_t src = (((size_t)b * HP + (h0 + row)) * HP + (w0 + cl)) * C + g * 8;
            *(uint4*)(Ash + p * 72 + g * 8) = *(const uint4*)(h1p + src);
        }
    }
    __syncthreads();

    us8 bc = *(const us8*)(W2r + ((size_t)(0 * 2 + khalf) * C + nbase + col) * 8);

    for (int chunk = 0; chunk < 9; ++chunk) {
        const int ii = chunk / 3, jj = chunk - ii * 3;
        const int pixbase = (rsel + ii) * 66 + jj;
#pragma unroll
        for (int ks = 0; ks < 4; ++ks) {
            const int kstep = chunk * 4 + ks;
            us8 bn;
            if (kstep < 35)
                bn = *(const us8*)(W2r + ((size_t)((kstep + 1) * 2 + khalf) * C + nbase + col) * 8);
            const int koff = ks * 16 + khalf * 8;
            bf16x8 a0 = __builtin_bit_cast(bf16x8, *(const us8*)(Ash + (pixbase + col) * 72 + koff));
            bf16x8 a1 = __builtin_bit_cast(bf16x8, *(const us8*)(Ash + (pixbase + col + 32) * 72 + koff));
            bf16x8 bv = __builtin_bit_cast(bf16x8, bc);
            acc[0] = __builtin_amdgcn_mfma_f32_32x32x16_bf16(a0, bv, acc[0], 0, 0, 0);
            acc[1] = __builtin_amdgcn_mfma_f32_32x32x16_bf16(a1, bv, acc[1], 0, 0, 0);
            bc = bn;
        }
    }

    const int n = nbase + col;
    const float bias = b2[n];
#pragma unroll
    for (int ai = 0; ai < 2; ++ai) {
#pragma unroll
        for (int r = 0; r < 16; ++r) {
            int m = mrow_base + ai * 32 + (r & 3) + ((r >> 2) << 3) + (khalf << 2);
            int h = h0 + (m >> 6), w = w0 + (m & 63);
            float val = fmaxf(acc[ai][r] + bias, 0.f);
            h2[(((size_t)b * HW + h) * HW + w) * C + n] = f2bf(val);
        }
    }
}

// ---------------- conv3 + NLM: A-tile-once, B from global (coalesced frags) ----
__global__ __launch_bounds__(256, 3) void conv3_mfma_kernel(
    const float* __restrict__ x, const unsigned short* __restrict__ h2,
    const unsigned short* __restrict__ Bg, const float* __restrict__ b3,
    float* __restrict__ y)
{
    __shared__ unsigned short Ash[264 * 72];
    __shared__ float red[4][64];

    const int t = threadIdx.x;
    const int lane = t & 63;
    const int wave = t >> 6;
    const int b   = blockIdx.z;
    const int ho0 = blockIdx.y * 2;
    const int wo0 = blockIdx.x * 64;

    const int col   = lane & 31;
    const int khalf = lane >> 5;
    const int mrow_base = (wave >> 1) * 64;
    const int nbase     = (wave & 1) * 96;
    const int rsel      = mrow_base >> 6;

    f32x16 acc[2][3];
#pragma unroll
    for (int mi = 0; mi < 2; ++mi)
#pragma unroll
        for (int ni = 0; ni < 3; ++ni)
#pragma unroll
            for (int r = 0; r < 16; ++r) acc[mi][ni][r] = 0.f;

    // stage full A-tile once: rows ho0+5..ho0+8, cols wo0+5..wo0+70 (clamped)
#pragma unroll
    for (int it = 0; it < 9; ++it) {
        int li = it * 256 + t;
        if (li < 264 * 8) {
            int p = li >> 3, g = li & 7;
            int row = p / 66, cl = p - row * 66;
            int ww = wo0 + 5 + cl; ww = ww < 255 ? ww : 255;
            size_t src = (((size_t)b * HW + (ho0 + 5 + row)) * HW + ww) * C + g * 8;
            *(uint4*)(Ash + p * 72 + g * 8) = *(const uint4*)(h2 + src);
        }
    }
    __syncthreads();

    us8 bc0 = *(const us8*)(Bg + ((size_t)(0 * 2 + khalf) * NPAD + nbase + col) * 8);
    us8 bc1 = *(const us8*)(Bg + ((size_t)(0 * 2 + khalf) * NPAD + nbase + 32 + col) * 8);
    us8 bc2 = *(const us8*)(Bg + ((size_t)(0 * 2 + khalf) * NPAD + nbase + 64 + col) * 8);

    for (int chunk = 0; chunk < 9; ++chunk) {
        const int ii = chunk / 3, jj = chunk - ii * 3;
        const int pixbase = (rsel + ii) * 66 + jj;
#pragma unroll
        for (int ks = 0; ks < 4; ++ks) {
            const int kstep = chunk * 4 + ks;
            us8 bn0, bn1, bn2;
            if (kstep < 35) {
                size_t base = ((size_t)((kstep + 1) * 2 + khalf) * NPAD + nbase + col) * 8;
                bn0 = *(const us8*)(Bg + base);
                bn1 = *(const us8*)(Bg + base + 32 * 8);
                bn2 = *(const us8*)(Bg + base + 64 * 8);
            }
            const int koff = ks * 16 + khalf * 8;
            bf16x8 a0 = __builtin_bit_cast(bf16x8, *(const us8*)(Ash + (pixbase + col) * 72 + koff));
            bf16x8 a1 = __builtin_bit_cast(bf16x8, *(const us8*)(Ash + (pixbase + col + 32) * 72 + koff));
            bf16x8 v0 = __builtin_bit_cast(bf16x8, bc0);
            bf16x8 v1 = __builtin_bit_cast(bf16x8, bc1);
            bf16x8 v2 = __builtin_bit_cast(bf16x8, bc2);
            acc[0][0] = __builtin_amdgcn_mfma_f32_32x32x16_bf16(a0, v0, acc[0][0], 0, 0, 0);
            acc[0][1] = __builtin_amdgcn_mfma_f32_32x32x16_bf16(a0, v1, acc[0][1], 0, 0, 0);
            acc[0][2] = __builtin_amdgcn_mfma_f32_32x32x16_bf16(a0, v2, acc[0][2], 0, 0, 0);
            acc[1][0] = __builtin_amdgcn_mfma_f32_32x32x16_bf16(a1, v0, acc[1][0], 0, 0, 0);
            acc[1][1] = __builtin_amdgcn_mfma_f32_32x32x16_bf16(a1, v1, acc[1][1], 0, 0, 0);
            acc[1][2] = __builtin_amdgcn_mfma_f32_32x32x16_bf16(a1, v2, acc[1][2], 0, 0, 0);
            bc0 = bn0; bc1 = bn1; bc2 = bn2;
        }
    }

    // ---- epilogue (unchanged, validated): y = sum_q (acc+b3[q]) * x-patch ----
    const int ho_pix = ho0 + (wave >> 1);
    const float* __restrict__ xplane = x + ((size_t)b << 16);

    int   qv[3], uo[3], vo[3];
    float b3v[3];
#pragma unroll
    for (int ni = 0; ni < 3; ++ni) {
        int q = nbase + ni * 32 + col;
        qv[ni] = q;
        int u = q / 13;
        uo[ni] = u;
        vo[ni] = q - u * 13;
        b3v[ni] = (q < 169) ? b3[q] : 0.f;
    }

    float partial[2][16];
#pragma unroll
    for (int mi = 0; mi < 2; ++mi)
#pragma unroll
        for (int r = 0; r < 16; ++r) {
            int mrow = mi * 32 + (r & 3) + ((r >> 2) << 3) + (khalf << 2);
            int wo_pix = wo0 + mrow;
            bool wok = wo_pix < HO;
            float p = 0.f;
#pragma unroll
            for (int ni = 0; ni < 3; ++ni) {
                if (qv[ni] < 169 && wok) {
                    float s = acc[mi][ni][r] + b3v[ni];
                    p += s * xplane[(ho_pix + uo[ni]) * HW + wo_pix + vo[ni]];
                }
            }
            partial[mi][r] = p;
        }

#pragma unroll
    for (int mi = 0; mi < 2; ++mi)
#pragma unroll
        for (int r = 0; r < 16; ++r) {
            float p = partial[mi][r];
#pragma unroll
            for (int d = 1; d < 32; d <<= 1) p += __shfl_xor(p, d, 64);
            partial[mi][r] = p;
        }

    if (col == 0) {
#pragma unroll
        for (int mi = 0; mi < 2; ++mi)
#pragma unroll
            for (int r = 0; r < 16; ++r) {
                int mrow = mi * 32 + (r & 3) + ((r >> 2) << 3) + (khalf << 2);
                red[wave][mrow] = partial[mi][r];
            }
    }
    __syncthreads();

    if (t < 128) {
        int row_sel = t >> 6, m = t & 63;
        float val = red[row_sel * 2][m] + red[row_sel * 2 + 1][m];
        int wo = wo0 + m, ho = ho0 + row_sel;
        if (wo < HO)
            y[((size_t)b * HO + ho) * HO + wo] = val;
    }
}

extern "C" void kernel_launch(void* const* d_in, const int* in_sizes, int n_in,
                              void* d_out, int out_size, void* d_ws, size_t ws_size,
                              hipStream_t stream) {
    const float* x  = (const float*)d_in[0];
    const float* W1 = (const float*)d_in[1];
    const float* b1 = (const float*)d_in[2];
    const float* W2 = (const float*)d_in[3];
    const float* b2 = (const float*)d_in[4];
    const float* W3 = (const float*)d_in[5];
    const float* b3 = (const float*)d_in[6];
    float* out = (float*)d_out;

    unsigned short* h1p = (unsigned short*)d_ws;                 // 8*258*258*64 bf16
    unsigned short* h2  = h1p + (size_t)BATCH * HP * HP * C;     // 8*256*256*64 bf16
    unsigned short* W2r = h2 + (size_t)BATCH * HW * HW * C;      // 36864 elems
    unsigned short* W3r = W2r + (size_t)36 * 2 * C * 8;          // 110592 elems

    repack_w2_kernel<<<144, 256, 0, stream>>>(W2, W2r);
    repack_w3_kernel<<<432, 256, 0, stream>>>(W3, W3r);
    conv1_kernel<<<(BATCH * HP * HP + 31) / 32, 256, 0, stream>>>(x, W1, b1, h1p);
    conv2_mfma_kernel<<<dim3(4, 128, 8), 256, 0, stream>>>(h1p, W2r, b2, h2);
    conv3_mfma_kernel<<<dim3(4, 122, 8), 256, 0, stream>>>(x, h2, W3r, b3, out);
}